// Round 2
// baseline (1561.330 us; speedup 1.0000x reference)
//
#include <hip/hip_runtime.h>
#include <float.h>

// Problem constants (LocalAttention): B=4, N=4096, DIM=1024, WINDOW=128.
// Reference bug faithfully exploited: v2 = k2, so the V projection (last 1024
// cols of w_qkv) is never used -> we only compute q and k.

#define B_SZ 4
#define SEQ 4096
#define DIM 1024
#define WIN 128
#define NWIN 32            // SEQ / WIN
#define TW  256            // 2*WIN (lookback + current)
#define NROWS (B_SZ * SEQ) // 16384

#define BM 128
#define BN 128
#define BK 16

// ---------------------------------------------------------------------------
// Generic fp32 NN GEMM: C[M,N] = A[M,K] * B[K,N] (+ bias). All dims assumed
// multiples of tile sizes (true for this problem). Grid: (N/BN, M/BM).
// ---------------------------------------------------------------------------
__global__ __launch_bounds__(256) void gemm_nn_kernel(
    const float* __restrict__ A, int lda,
    const float* __restrict__ Bm, int ldb,
    float* __restrict__ C, int ldc,
    const float* __restrict__ bias, int K)
{
    __shared__ float As[BK][BM];   // transposed A tile: As[k][m]
    __shared__ float Bs[BK][BN];

    const int bm = blockIdx.y * BM;
    const int bn = blockIdx.x * BN;
    const int tid = threadIdx.x;
    const int tx = tid & 15;       // 0..15 -> 8 cols each
    const int ty = tid >> 4;       // 0..15 -> 8 rows each

    float acc[8][8];
#pragma unroll
    for (int i = 0; i < 8; ++i)
#pragma unroll
        for (int j = 0; j < 8; ++j) acc[i][j] = 0.f;

    for (int k0 = 0; k0 < K; k0 += BK) {
        // A tile: 128 rows x 16 cols. 512 float4 loads, 2 per thread.
#pragma unroll
        for (int i = 0; i < 2; ++i) {
            int idx = tid + 256 * i;          // 0..511
            int r   = idx >> 2;               // 0..127
            int c4  = (idx & 3) * 4;          // 0,4,8,12
            float4 v = *(const float4*)&A[(size_t)(bm + r) * lda + k0 + c4];
            As[c4 + 0][r] = v.x; As[c4 + 1][r] = v.y;
            As[c4 + 2][r] = v.z; As[c4 + 3][r] = v.w;
        }
        // B tile: 16 rows x 128 cols. 512 float4 loads, 2 per thread.
#pragma unroll
        for (int i = 0; i < 2; ++i) {
            int idx = tid + 256 * i;
            int r   = idx >> 5;               // 0..15
            int c4  = (idx & 31) * 4;         // 0..124
            float4 v = *(const float4*)&Bm[(size_t)(k0 + r) * ldb + bn + c4];
            *(float4*)&Bs[r][c4] = v;
        }
        __syncthreads();

#pragma unroll
        for (int kk = 0; kk < BK; ++kk) {
            float a[8], b[8];
#pragma unroll
            for (int i = 0; i < 8; ++i) a[i] = As[kk][ty * 8 + i];
#pragma unroll
            for (int j = 0; j < 8; ++j) b[j] = Bs[kk][tx * 8 + j];
#pragma unroll
            for (int i = 0; i < 8; ++i)
#pragma unroll
                for (int j = 0; j < 8; ++j) acc[i][j] += a[i] * b[j];
        }
        __syncthreads();
    }

#pragma unroll
    for (int i = 0; i < 8; ++i) {
        int r = bm + ty * 8 + i;
#pragma unroll
        for (int j = 0; j < 8; j += 4) {
            int c = bn + tx * 8 + j;
            float4 v = make_float4(acc[i][j], acc[i][j+1], acc[i][j+2], acc[i][j+3]);
            if (bias) {
                v.x += bias[c]; v.y += bias[c+1]; v.z += bias[c+2]; v.w += bias[c+3];
            }
            *(float4*)&C[(size_t)r * ldc + c] = v;
        }
    }
}

// ---------------------------------------------------------------------------
// sim = q . k2^T * scale, masked. One block = one window x one 128-col tile.
// qk layout: [16384][2048], q at col 0, k at col 1024 (ld 2048).
// k2 row j (global 0..255) of window w = k batch-row (w-1)*128 + j (zeros if <0).
// ---------------------------------------------------------------------------
__global__ __launch_bounds__(256) void sim_kernel(
    const float* __restrict__ qk, float* __restrict__ attn)
{
    const int win = blockIdx.y;          // 0..127  (b*32 + w)
    const int b   = win >> 5;
    const int w   = win & 31;
    const int ct  = blockIdx.x;          // 0..1 (column tile of 128 within 256)

    __shared__ float As[BK][BM];
    __shared__ float Bs[BK][BN];

    const int tid = threadIdx.x;
    const int tx = tid & 15;
    const int ty = tid >> 4;

    const float* qbase = qk + (size_t)(b * SEQ + w * WIN) * (2 * DIM);
    const float* kbase = qk + (size_t)(b * SEQ) * (2 * DIM) + DIM;
    const int krow0 = (w - 1) * WIN + ct * BN;   // batch-row of first k2 row here

    float acc[8][8];
#pragma unroll
    for (int i = 0; i < 8; ++i)
#pragma unroll
        for (int j = 0; j < 8; ++j) acc[i][j] = 0.f;

    for (int k0 = 0; k0 < DIM; k0 += BK) {
        // q tile 128x16
#pragma unroll
        for (int i = 0; i < 2; ++i) {
            int idx = tid + 256 * i;
            int r   = idx >> 2;
            int c4  = (idx & 3) * 4;
            float4 v = *(const float4*)&qbase[(size_t)r * (2 * DIM) + k0 + c4];
            As[c4 + 0][r] = v.x; As[c4 + 1][r] = v.y;
            As[c4 + 2][r] = v.z; As[c4 + 3][r] = v.w;
        }
        // k2 tile 128 rows x 16 cols -> transposed into Bs[k][col]
#pragma unroll
        for (int i = 0; i < 2; ++i) {
            int idx = tid + 256 * i;
            int r   = idx >> 2;               // local col (= k2 row) 0..127
            int c4  = (idx & 3) * 4;
            int rb  = krow0 + r;
            float4 v = make_float4(0.f, 0.f, 0.f, 0.f);
            if (rb >= 0)
                v = *(const float4*)&kbase[(size_t)rb * (2 * DIM) + k0 + c4];
            Bs[c4 + 0][r] = v.x; Bs[c4 + 1][r] = v.y;
            Bs[c4 + 2][r] = v.z; Bs[c4 + 3][r] = v.w;
        }
        __syncthreads();

#pragma unroll
        for (int kk = 0; kk < BK; ++kk) {
            float a[8], bb[8];
#pragma unroll
            for (int i = 0; i < 8; ++i) a[i] = As[kk][ty * 8 + i];
#pragma unroll
            for (int j = 0; j < 8; ++j) bb[j] = Bs[kk][tx * 8 + j];
#pragma unroll
            for (int i = 0; i < 8; ++i)
#pragma unroll
                for (int j = 0; j < 8; ++j) acc[i][j] += a[i] * bb[j];
        }
        __syncthreads();
    }

    const float scale = 0.03125f;  // DIM^-0.5 = 1/32
#pragma unroll
    for (int i = 0; i < 8; ++i) {
        int qi = ty * 8 + i;
#pragma unroll
        for (int j = 0; j < 8; ++j) {
            int jc = ct * BN + tx * 8 + j;
            // causal: mask where jc > qi + WIN  (triu k = j-i+1)
            float v = (jc > qi + WIN) ? -FLT_MAX : acc[i][j] * scale;
            attn[((size_t)win * WIN + qi) * TW + jc] = v;
        }
    }
}

// ---------------------------------------------------------------------------
// Row softmax over 256 cols, in place. One wave per row, 4 rows per block.
// ---------------------------------------------------------------------------
__global__ __launch_bounds__(256) void softmax_kernel(float* __restrict__ attn)
{
    const int row  = blockIdx.x * 4 + (threadIdx.x >> 6);
    const int lane = threadIdx.x & 63;
    float* p = attn + (size_t)row * TW;

    float4 v = *(float4*)&p[lane * 4];
    float m = fmaxf(fmaxf(v.x, v.y), fmaxf(v.z, v.w));
#pragma unroll
    for (int off = 32; off; off >>= 1) m = fmaxf(m, __shfl_xor(m, off));

    float e0 = expf(v.x - m), e1 = expf(v.y - m);
    float e2 = expf(v.z - m), e3 = expf(v.w - m);
    float s = e0 + e1 + e2 + e3;
#pragma unroll
    for (int off = 32; off; off >>= 1) s += __shfl_xor(s, off);

    float inv = 1.f / s;
    float4 o = make_float4(e0 * inv, e1 * inv, e2 * inv, e3 * inv);
    *(float4*)&p[lane * 4] = o;
}

// ---------------------------------------------------------------------------
// out = attn @ v2, where v2 = k2 (reference bug). One block = window x 128-col
// tile of DIM. K = 256 (the two k blocks), with zero rows for w==0 lookback.
// ---------------------------------------------------------------------------
__global__ __launch_bounds__(256) void pv_kernel(
    const float* __restrict__ attn, const float* __restrict__ qk,
    float* __restrict__ aout)
{
    const int win = blockIdx.y;
    const int b   = win >> 5;
    const int w   = win & 31;
    const int ct  = blockIdx.x;          // 0..7

    __shared__ float As[BK][BM];
    __shared__ float Bs[BK][BN];

    const int tid = threadIdx.x;
    const int tx = tid & 15;
    const int ty = tid >> 4;

    const float* abase = attn + (size_t)win * WIN * TW;          // 128 x 256
    const float* kbase = qk + (size_t)(b * SEQ) * (2 * DIM) + DIM;

    float acc[8][8];
#pragma unroll
    for (int i = 0; i < 8; ++i)
#pragma unroll
        for (int j = 0; j < 8; ++j) acc[i][j] = 0.f;

    for (int k0 = 0; k0 < TW; k0 += BK) {
        // attn tile 128x16
#pragma unroll
        for (int i = 0; i < 2; ++i) {
            int idx = tid + 256 * i;
            int r   = idx >> 2;
            int c4  = (idx & 3) * 4;
            float4 v = *(const float4*)&abase[(size_t)r * TW + k0 + c4];
            As[c4 + 0][r] = v.x; As[c4 + 1][r] = v.y;
            As[c4 + 2][r] = v.z; As[c4 + 3][r] = v.w;
        }
        // k2 tile: 16 rows (k2 rows k0..k0+15) x 128 cols (dims ct*128..)
#pragma unroll
        for (int i = 0; i < 2; ++i) {
            int idx = tid + 256 * i;
            int r   = idx >> 5;               // 0..15
            int c4  = (idx & 31) * 4;
            int rb  = (w - 1) * WIN + k0 + r;
            float4 v = make_float4(0.f, 0.f, 0.f, 0.f);
            if (rb >= 0)
                v = *(const float4*)&kbase[(size_t)rb * (2 * DIM) + ct * BN + c4];
            *(float4*)&Bs[r][c4] = v;
        }
        __syncthreads();

#pragma unroll
        for (int kk = 0; kk < BK; ++kk) {
            float a[8], bb[8];
#pragma unroll
            for (int i = 0; i < 8; ++i) a[i] = As[kk][ty * 8 + i];
#pragma unroll
            for (int j = 0; j < 8; ++j) bb[j] = Bs[kk][tx * 8 + j];
#pragma unroll
            for (int i = 0; i < 8; ++i)
#pragma unroll
                for (int j = 0; j < 8; ++j) acc[i][j] += a[i] * bb[j];
        }
        __syncthreads();
    }

#pragma unroll
    for (int i = 0; i < 8; ++i) {
        int r = b * SEQ + w * WIN + ty * 8 + i;
#pragma unroll
        for (int j = 0; j < 8; j += 4) {
            int c = ct * BN + tx * 8 + j;
            float4 v = make_float4(acc[i][j], acc[i][j+1], acc[i][j+2], acc[i][j+3]);
            *(float4*)&aout[(size_t)r * DIM + c] = v;
        }
    }
}

// ---------------------------------------------------------------------------
extern "C" void kernel_launch(void* const* d_in, const int* in_sizes, int n_in,
                              void* d_out, int out_size, void* d_ws, size_t ws_size,
                              hipStream_t stream)
{
    const float* x     = (const float*)d_in[0];
    const float* w_qkv = (const float*)d_in[1];
    const float* w_out = (const float*)d_in[2];
    const float* b_out = (const float*)d_in[3];
    float* out = (float*)d_out;

    // Workspace layout (floats):
    float* qk   = (float*)d_ws;                          // 16384 x 2048 (q|k)
    float* attn = qk   + (size_t)NROWS * 2 * DIM;        // 16384 x 256
    float* aout = attn + (size_t)NROWS * TW;             // 16384 x 1024

    // 1) q|k projection: x(16384x1024) @ w_qkv[:, :2048] -> qk (ld 2048).
    //    v columns skipped entirely (reference: v2 = k2).
    gemm_nn_kernel<<<dim3((2 * DIM) / BN, NROWS / BM), 256, 0, stream>>>(
        x, DIM, w_qkv, 3 * DIM, qk, 2 * DIM, nullptr, DIM);

    // 2) sim = q.k2^T * scale with causal mask -> attn buffer (pre-softmax)
    sim_kernel<<<dim3(2, B_SZ * NWIN), 256, 0, stream>>>(qk, attn);

    // 3) softmax rows (in place)
    softmax_kernel<<<dim3(NROWS / 4), 256, 0, stream>>>(attn);

    // 4) out = attn @ k2 -> aout
    pv_kernel<<<dim3(DIM / BN, B_SZ * NWIN), 256, 0, stream>>>(attn, qk, aout);

    // 5) final = aout @ w_out + b_out -> d_out
    gemm_nn_kernel<<<dim3(DIM / BN, NROWS / BM), 256, 0, stream>>>(
        aout, DIM, w_out, DIM, out, DIM, b_out, DIM);
}

// Round 3
// 364.941 us; speedup vs baseline: 4.2783x; 4.2783x over previous
//
#include <hip/hip_runtime.h>
#include <float.h>

// LocalAttention: B=4, N=4096, DIM=1024, WINDOW=128. v2=k2 reference bug
// exploited (V projection dead). All matmuls via bf16 MFMA 16x16x32, fp32 acc.

#define B_SZ 4
#define SEQ 4096
#define DIM 1024
#define WIN 128
#define NWIN 32
#define TW 256
#define NROWS (B_SZ * SEQ)     // 16384
#define KPAD 4224              // 128 zero rows + 4096 tokens per batch

typedef float f32x4 __attribute__((ext_vector_type(4)));
typedef __bf16 bf16x8 __attribute__((ext_vector_type(8)));

__device__ __forceinline__ unsigned short f2b(float f) {
    unsigned int u = __float_as_uint(f);
    u += 0x7FFF + ((u >> 16) & 1);          // round-to-nearest-even
    return (unsigned short)(u >> 16);
}

__device__ __forceinline__ void gld_lds16(const unsigned short* g, unsigned short* l) {
    __builtin_amdgcn_global_load_lds(
        (const __attribute__((address_space(1))) void*)g,
        (__attribute__((address_space(3))) void*)l, 16, 0, 0);
}

// ---------------------------------------------------------------------------
// Core: C(128x128) = A(128xK) * Bt(128xK)^T, both bf16 row-major K-contiguous.
// 256 threads = 4 waves (2x2), each wave a 64x64 sub-tile = 4x4 frags 16x16.
// LDS linear [128][64] per operand, staged via global_load_lds width 16
// (m97 structure). A/Bt row strides must be multiples of 8 elements.
// ---------------------------------------------------------------------------
__device__ __forceinline__ void mfma_core(
    const unsigned short* __restrict__ A, int lda,
    const unsigned short* __restrict__ Bt, int ldb, int K,
    unsigned short* As, unsigned short* Bs, f32x4 (&acc)[4][4])
{
    const int tid = threadIdx.x;
    const int wv = tid >> 6, lane = tid & 63;
    const int wr = wv >> 1, wc = wv & 1;

#pragma unroll
    for (int m = 0; m < 4; ++m)
#pragma unroll
        for (int n = 0; n < 4; ++n) acc[m][n] = (f32x4){0.f, 0.f, 0.f, 0.f};

    for (int k0 = 0; k0 < K; k0 += 64) {
        // stage A tile rows [wv*32, wv*32+32): 4 insts x 1KB (8 rows each)
#pragma unroll
        for (int it = 0; it < 4; ++it) {
            int rbase = wv * 32 + it * 8;
            const unsigned short* g =
                A + (size_t)(rbase + (lane >> 3)) * lda + k0 + (lane & 7) * 8;
            gld_lds16(g, As + rbase * 64);
        }
#pragma unroll
        for (int it = 0; it < 4; ++it) {
            int rbase = wv * 32 + it * 8;
            const unsigned short* g =
                Bt + (size_t)(rbase + (lane >> 3)) * ldb + k0 + (lane & 7) * 8;
            gld_lds16(g, Bs + rbase * 64);
        }
        __syncthreads();   // compiler drains vmcnt before s_barrier

#pragma unroll
        for (int ks = 0; ks < 2; ++ks) {
            bf16x8 af[4], bfr[4];
            const int kof = ks * 32 + (lane >> 4) * 8;
#pragma unroll
            for (int m = 0; m < 4; ++m)
                af[m] = *(const bf16x8*)(As + (wr * 64 + m * 16 + (lane & 15)) * 64 + kof);
#pragma unroll
            for (int n = 0; n < 4; ++n)
                bfr[n] = *(const bf16x8*)(Bs + (wc * 64 + n * 16 + (lane & 15)) * 64 + kof);
#pragma unroll
            for (int m = 0; m < 4; ++m)
#pragma unroll
                for (int n = 0; n < 4; ++n)
                    acc[m][n] = __builtin_amdgcn_mfma_f32_16x16x32_bf16(
                        af[m], bfr[n], acc[m][n], 0, 0, 0);
        }
        __syncthreads();
    }
}

// C/D frag mapping (verified m89/m91): col = lane&15, row = (lane>>4)*4 + r.

// ---------------------------------------------------------------------------
// Prepass kernels
// ---------------------------------------------------------------------------
__global__ __launch_bounds__(256) void k_prep_x(const float* __restrict__ x,
                                                unsigned short* __restrict__ xb)
{
    int i = blockIdx.x * 256 + threadIdx.x;      // 8 elems per thread
    float4 a = *(const float4*)&x[(size_t)i * 8];
    float4 b = *(const float4*)&x[(size_t)i * 8 + 4];
    ushort4 lo, hi;
    lo.x = f2b(a.x); lo.y = f2b(a.y); lo.z = f2b(a.z); lo.w = f2b(a.w);
    hi.x = f2b(b.x); hi.y = f2b(b.y); hi.z = f2b(b.z); hi.w = f2b(b.w);
    *(ushort4*)&xb[(size_t)i * 8] = lo;
    *(ushort4*)&xb[(size_t)i * 8 + 4] = hi;
}

// dst[c][r] = bf16(src[r][col0+c]); grid (C/32, R/32)
__global__ __launch_bounds__(256) void k_transpose(const float* __restrict__ src,
    int src_ld, int col0, int R, unsigned short* __restrict__ dst)
{
    __shared__ float T[32][33];
    const int r0 = blockIdx.y * 32, c0 = blockIdx.x * 32;
    const int cx = threadIdx.x & 31, ry = threadIdx.x >> 5;   // ry 0..7
#pragma unroll
    for (int i = 0; i < 4; ++i)
        T[ry + 8 * i][cx] = src[(size_t)(r0 + ry + 8 * i) * src_ld + col0 + c0 + cx];
    __syncthreads();
#pragma unroll
    for (int i = 0; i < 4; ++i)
        dst[(size_t)(c0 + ry + 8 * i) * R + r0 + cx] = f2b(T[cx][ry + 8 * i]);
}

// zero the 128-token lookback pads (ws is poisoned 0xAA before every launch)
__global__ __launch_bounds__(256) void k_zero_kpad(unsigned short* __restrict__ kbuf)
{
    int t = blockIdx.x * 256 + threadIdx.x;       // 65536 threads x 16B
    int b = t >> 14, r = t & 16383;
    float4 z = {0.f, 0.f, 0.f, 0.f};
    *(float4*)&kbuf[(size_t)b * KPAD * DIM + (size_t)r * 8] = z;
}

__global__ __launch_bounds__(256) void k_zero_ktpad(unsigned short* __restrict__ ktr)
{
    int t = blockIdx.x * 256 + threadIdx.x;       // 65536 threads x 16B
    int b = t >> 14, rem = t & 16383;
    int d = rem >> 4, s = rem & 15;
    float4 z = {0.f, 0.f, 0.f, 0.f};
    *(float4*)&ktr[((size_t)b * DIM + d) * KPAD + s * 8] = z;
}

// ---------------------------------------------------------------------------
// GEMM kernels
// ---------------------------------------------------------------------------
// qk-proj: xb(16384x1024) x wqkvT(2048x1024)^T. n<1024 -> qbuf; else k: write
// kbuf[b][128+tok][d] and ktrans[b][d][128+tok].
__global__ __launch_bounds__(256) void k_gemm_qk(
    const unsigned short* __restrict__ xb, const unsigned short* __restrict__ wqkvT,
    unsigned short* __restrict__ qbuf, unsigned short* __restrict__ kbuf,
    unsigned short* __restrict__ ktr)
{
    __shared__ unsigned short As[128 * 64], Bs[128 * 64];
    f32x4 acc[4][4];
    const int bm = blockIdx.y * 128, bn = blockIdx.x * 128;
    mfma_core(xb + (size_t)bm * DIM, DIM, wqkvT + (size_t)bn * DIM, DIM, DIM, As, Bs, acc);

    const int tid = threadIdx.x, wv = tid >> 6, lane = tid & 63;
    const int wr = wv >> 1, wc = wv & 1;
#pragma unroll
    for (int m = 0; m < 4; ++m) {
        const int row0 = bm + wr * 64 + m * 16 + (lane >> 4) * 4;
#pragma unroll
        for (int n = 0; n < 4; ++n) {
            const int col = bn + wc * 64 + n * 16 + (lane & 15);
            if (col < DIM) {
#pragma unroll
                for (int r = 0; r < 4; ++r)
                    qbuf[(size_t)(row0 + r) * DIM + col] = f2b(acc[m][n][r]);
            } else {
                const int d = col - DIM;
                const int b = row0 >> 12, tok0 = row0 & 4095;
#pragma unroll
                for (int r = 0; r < 4; ++r)
                    kbuf[((size_t)b * KPAD + 128 + tok0 + r) * DIM + d] = f2b(acc[m][n][r]);
                ushort4 kt;
                kt.x = f2b(acc[m][n][0]); kt.y = f2b(acc[m][n][1]);
                kt.z = f2b(acc[m][n][2]); kt.w = f2b(acc[m][n][3]);
                *(ushort4*)&ktr[((size_t)b * DIM + d) * KPAD + 128 + tok0] = kt;
            }
        }
    }
}

// sim = q . k2^T * scale, masked -> fp32. grid (2, 128)
__global__ __launch_bounds__(256) void k_sim(
    const unsigned short* __restrict__ qbuf, const unsigned short* __restrict__ kbuf,
    float* __restrict__ sim)
{
    __shared__ unsigned short As[128 * 64], Bs[128 * 64];
    f32x4 acc[4][4];
    const int win = blockIdx.y, ct = blockIdx.x;
    const int b = win >> 5, w = win & 31;
    const unsigned short* Ap = qbuf + ((size_t)b * SEQ + w * WIN) * DIM;
    const unsigned short* Bp = kbuf + ((size_t)b * KPAD + w * WIN + ct * 128) * DIM;
    mfma_core(Ap, DIM, Bp, DIM, DIM, As, Bs, acc);

    const int tid = threadIdx.x, wv = tid >> 6, lane = tid & 63;
    const int wr = wv >> 1, wc = wv & 1;
    const float scale = 0.03125f;
#pragma unroll
    for (int m = 0; m < 4; ++m) {
        const int qi0 = wr * 64 + m * 16 + (lane >> 4) * 4;
#pragma unroll
        for (int n = 0; n < 4; ++n) {
            const int jc = ct * 128 + wc * 64 + n * 16 + (lane & 15);
#pragma unroll
            for (int r = 0; r < 4; ++r) {
                const int qi = qi0 + r;
                float v = (jc > qi + WIN) ? -FLT_MAX : acc[m][n][r] * scale;
                sim[((size_t)win * WIN + qi) * TW + jc] = v;
            }
        }
    }
}

// row softmax over 256, fp32 in -> bf16 out. 1 wave/row, 4 rows/block.
__global__ __launch_bounds__(256) void k_softmax(const float* __restrict__ sim,
                                                 unsigned short* __restrict__ attnb)
{
    const int row = blockIdx.x * 4 + (threadIdx.x >> 6);
    const int lane = threadIdx.x & 63;
    const float* p = sim + (size_t)row * TW;
    float4 v = *(const float4*)&p[lane * 4];
    float m = fmaxf(fmaxf(v.x, v.y), fmaxf(v.z, v.w));
#pragma unroll
    for (int off = 32; off; off >>= 1) m = fmaxf(m, __shfl_xor(m, off));
    float e0 = expf(v.x - m), e1 = expf(v.y - m);
    float e2 = expf(v.z - m), e3 = expf(v.w - m);
    float s = e0 + e1 + e2 + e3;
#pragma unroll
    for (int off = 32; off; off >>= 1) s += __shfl_xor(s, off);
    float inv = 1.f / s;
    ushort4 o;
    o.x = f2b(e0 * inv); o.y = f2b(e1 * inv); o.z = f2b(e2 * inv); o.w = f2b(e3 * inv);
    *(ushort4*)&attnb[(size_t)row * TW + lane * 4] = o;
}

// PV: attnb(128x256) @ k2 via ktrans (Bt = ktrans rows, K = 256 padded tokens)
__global__ __launch_bounds__(256) void k_pv(
    const unsigned short* __restrict__ attnb, const unsigned short* __restrict__ ktr,
    unsigned short* __restrict__ aout)
{
    __shared__ unsigned short As[128 * 64], Bs[128 * 64];
    f32x4 acc[4][4];
    const int win = blockIdx.y, ct = blockIdx.x;
    const int b = win >> 5, w = win & 31;
    const unsigned short* Ap = attnb + (size_t)win * WIN * TW;
    const unsigned short* Bp = ktr + ((size_t)b * DIM + ct * 128) * KPAD + w * WIN;
    mfma_core(Ap, TW, Bp, KPAD, TW, As, Bs, acc);

    const int tid = threadIdx.x, wv = tid >> 6, lane = tid & 63;
    const int wr = wv >> 1, wc = wv & 1;
#pragma unroll
    for (int m = 0; m < 4; ++m) {
        const int row0 = wr * 64 + m * 16 + (lane >> 4) * 4;
#pragma unroll
        for (int n = 0; n < 4; ++n) {
            const int col = ct * 128 + wc * 64 + n * 16 + (lane & 15);
#pragma unroll
            for (int r = 0; r < 4; ++r)
                aout[((size_t)b * SEQ + w * WIN + row0 + r) * DIM + col] =
                    f2b(acc[m][n][r]);
        }
    }
}

// out-proj: aout @ w_out^T + bias -> fp32 d_out
__global__ __launch_bounds__(256) void k_out(
    const unsigned short* __restrict__ aout, const unsigned short* __restrict__ woutT,
    const float* __restrict__ bias, float* __restrict__ out)
{
    __shared__ unsigned short As[128 * 64], Bs[128 * 64];
    f32x4 acc[4][4];
    const int bm = blockIdx.y * 128, bn = blockIdx.x * 128;
    mfma_core(aout + (size_t)bm * DIM, DIM, woutT + (size_t)bn * DIM, DIM, DIM, As, Bs, acc);

    const int tid = threadIdx.x, wv = tid >> 6, lane = tid & 63;
    const int wr = wv >> 1, wc = wv & 1;
#pragma unroll
    for (int m = 0; m < 4; ++m) {
        const int row0 = bm + wr * 64 + m * 16 + (lane >> 4) * 4;
#pragma unroll
        for (int n = 0; n < 4; ++n) {
            const int col = bn + wc * 64 + n * 16 + (lane & 15);
            const float bb = bias[col];
#pragma unroll
            for (int r = 0; r < 4; ++r)
                out[(size_t)(row0 + r) * DIM + col] = acc[m][n][r] + bb;
        }
    }
}

// ---------------------------------------------------------------------------
extern "C" void kernel_launch(void* const* d_in, const int* in_sizes, int n_in,
                              void* d_out, int out_size, void* d_ws, size_t ws_size,
                              hipStream_t stream)
{
    const float* x     = (const float*)d_in[0];
    const float* w_qkv = (const float*)d_in[1];
    const float* w_out = (const float*)d_in[2];
    const float* b_out = (const float*)d_in[3];
    float* out = (float*)d_out;

    char* p = (char*)d_ws;
    unsigned short* xb    = (unsigned short*)p; p += (size_t)NROWS * DIM * 2;
    unsigned short* wqkvT = (unsigned short*)p; p += (size_t)2 * DIM * DIM * 2;
    unsigned short* woutT = (unsigned short*)p; p += (size_t)DIM * DIM * 2;
    unsigned short* qbuf  = (unsigned short*)p; p += (size_t)NROWS * DIM * 2;
    unsigned short* kbuf  = (unsigned short*)p; p += (size_t)B_SZ * KPAD * DIM * 2;
    unsigned short* ktr   = (unsigned short*)p; p += (size_t)B_SZ * DIM * KPAD * 2;
    float*          simb  = (float*)p;          p += (size_t)NROWS * TW * 4;
    unsigned short* attnb = (unsigned short*)p; p += (size_t)NROWS * TW * 2;
    unsigned short* aout  = (unsigned short*)p; p += (size_t)NROWS * DIM * 2;

    k_prep_x<<<NROWS * DIM / 8 / 256, 256, 0, stream>>>(x, xb);
    k_transpose<<<dim3(2 * DIM / 32, DIM / 32), 256, 0, stream>>>(w_qkv, 3 * DIM, 0, DIM, wqkvT);
    k_transpose<<<dim3(DIM / 32, DIM / 32), 256, 0, stream>>>(w_out, DIM, 0, DIM, woutT);
    k_zero_kpad<<<256, 256, 0, stream>>>(kbuf);
    k_zero_ktpad<<<256, 256, 0, stream>>>(ktr);

    k_gemm_qk<<<dim3(2 * DIM / 128, NROWS / 128), 256, 0, stream>>>(xb, wqkvT, qbuf, kbuf, ktr);
    k_sim<<<dim3(2, B_SZ * NWIN), 256, 0, stream>>>(qbuf, kbuf, simb);
    k_softmax<<<NROWS / 4, 256, 0, stream>>>(simb, attnb);
    k_pv<<<dim3(DIM / 128, B_SZ * NWIN), 256, 0, stream>>>(attnb, ktr, aout);
    k_out<<<dim3(DIM / 128, NROWS / 128), 256, 0, stream>>>(aout, woutT, b_out, out);
}